// Round 9
// baseline (69.469 us; speedup 1.0000x reference)
//
#include <hip/hip_runtime.h>

#define CH 64

typedef _Float16 half8  __attribute__((ext_vector_type(8)));
typedef _Float16 half2v __attribute__((ext_vector_type(2)));
typedef __fp16   fp16x2 __attribute__((ext_vector_type(2)));
typedef float    f32x4  __attribute__((ext_vector_type(4)));
typedef float    f32x2  __attribute__((ext_vector_type(2)));

// pack 2 f32 -> half2 (RTZ, single VALU op)
__device__ __forceinline__ half2v pk(float a, float b) {
    fp16x2 r = __builtin_amdgcn_cvt_pkrtz(a, b);
    return __builtin_bit_cast(half2v, r);
}

// ---------------------------------------------------------------------------
// Kernel 0: prepack W (f32 [64][64]) into fp16 MFMA B-fragments.
// ---------------------------------------------------------------------------
__global__ __launch_bounds__(512) void prepack_w(
    const float4* __restrict__ Wf4,   // [64*16]
    half8* __restrict__ Whp8)         // [512]
{
    const int t = threadIdx.x;        // 0..511
    const int o    = t & 63;
    const int grp  = t >> 6;          // 0..7
    const int kgrp = grp & 3;
    const int ck   = grp >> 2;
    const int c4   = ck * 8 + kgrp * 2;       // float4 index
    float4 a = Wf4[o * 16 + c4];
    float4 b = Wf4[o * 16 + c4 + 1];
    half8 h;
    half2v p0 = pk(a.x, a.y), p1 = pk(a.z, a.w);
    half2v p2 = pk(b.x, b.y), p3 = pk(b.z, b.w);
    h[0]=p0[0]; h[1]=p0[1]; h[2]=p1[0]; h[3]=p1[1];
    h[4]=p2[0]; h[5]=p2[1]; h[6]=p3[0]; h[7]=p3[1];
    Whp8[t] = h;
}

// ---------------------------------------------------------------------------
// Kernel 1: voxel MLP via MFMA fp16 (f32 accumulate), prepacked W.
// Output row m: 32 dwords, dword j = (h[j], h[j+32]) fp16 pair.
// ---------------------------------------------------------------------------
__global__ __launch_bounds__(256) void voxel_mlp_mfma(
    const int4*   __restrict__ vi4,
    const float4* __restrict__ vf4,
    const half8*  __restrict__ Whp8,
    const float*  __restrict__ gamma,
    const float*  __restrict__ beta,
    const float*  __restrict__ bn_mean,
    const float*  __restrict__ bn_var,
    unsigned*     __restrict__ Hvp,
    float4*       __restrict__ Vxyz,
    int M)
{
    const int t     = threadIdx.x;
    const int lane  = t & 63;
    const int wv    = t >> 6;
    const int row16 = lane & 15;
    const int kgrp  = lane >> 4;
    const int blockRow = blockIdx.x * 64;

    if (t < 64) {
        int r = blockRow + t;
        if (r < M) {
            int4 vi = vi4[r];
            float4 vx;
            vx.x = ((float)vi.w + 0.5f) * 0.1f;
            vx.y = ((float)vi.z + 0.5f) * 0.1f - 40.0f;
            vx.z = ((float)vi.y + 0.5f) * 0.2f - 3.0f;
            vx.w = 0.0f;
            Vxyz[r] = vx;
        }
    }

    // B fragments: straight 16B loads, no conversion
    half8 bfrag[4][2];
    #pragma unroll
    for (int ck = 0; ck < 2; ++ck) {
        #pragma unroll
        for (int ot = 0; ot < 4; ++ot)
            bfrag[ot][ck] = Whp8[(ck * 4 + kgrp) * 64 + ot * 16 + row16];
    }

    // A fragments: v_features rows (f32 -> fp16 via pkrtz)
    const int rbase = blockRow + wv * 16;
    int rc = rbase + row16; if (rc > M - 1) rc = M - 1;
    half8 afrag[2];
    #pragma unroll
    for (int ck = 0; ck < 2; ++ck) {
        int c4 = ck * 8 + kgrp * 2;
        float4 a = vf4[rc * 16 + c4];
        float4 b = vf4[rc * 16 + c4 + 1];
        half8 h;
        half2v p0 = pk(a.x, a.y), p1 = pk(a.z, a.w);
        half2v p2 = pk(b.x, b.y), p3 = pk(b.z, b.w);
        h[0]=p0[0]; h[1]=p0[1]; h[2]=p1[0]; h[3]=p1[1];
        h[4]=p2[0]; h[5]=p2[1]; h[6]=p3[0]; h[7]=p3[1];
        afrag[ck] = h;
    }

    f32x4 acc[4] = {{0.f,0.f,0.f,0.f},{0.f,0.f,0.f,0.f},{0.f,0.f,0.f,0.f},{0.f,0.f,0.f,0.f}};
    #pragma unroll
    for (int ot = 0; ot < 4; ++ot) {
        acc[ot] = __builtin_amdgcn_mfma_f32_16x16x32_f16(afrag[0], bfrag[ot][0], acc[ot], 0, 0, 0);
        acc[ot] = __builtin_amdgcn_mfma_f32_16x16x32_f16(afrag[1], bfrag[ot][1], acc[ot], 0, 0, 0);
    }

    float sc[4], sh[4];
    #pragma unroll
    for (int ot = 0; ot < 4; ++ot) {
        int o = ot * 16 + row16;
        float s = gamma[o] * rsqrtf(bn_var[o] + 1e-5f);
        sc[ot] = s;
        sh[ot] = beta[o] - bn_mean[o] * s;
    }

    #pragma unroll
    for (int reg = 0; reg < 4; ++reg) {
        int row = rbase + kgrp * 4 + reg;
        if (row < M) {
            #pragma unroll
            for (int ot = 0; ot < 2; ++ot) {
                float v0 = fmaxf(fmaf(acc[ot][reg],     sc[ot],     sh[ot]),     0.f);
                float v1 = fmaxf(fmaf(acc[ot + 2][reg], sc[ot + 2], sh[ot + 2]), 0.f);
                half2v p = pk(v0, v1);
                *reinterpret_cast<half2v*>(&Hvp[row * 32 + ot * 16 + row16]) = p;
            }
        }
    }
}

// ---------------------------------------------------------------------------
// Kernel 2: pooling. 2 points per wave, mask-predicated gathers.
// Streams (p_features, out) are NON-TEMPORAL so they don't evict the hot
// Hv table from L2 (gather is L2-miss-bound, Little's law).
// ---------------------------------------------------------------------------
__device__ __forceinline__ void pool_point_compute(
    int n, int g, int k, int q0,
    float wsel, float mk, const uint2* h01,
    f32x2 pf, float* __restrict__ out, bool doStore)
{
    float den = mk;
    den += __shfl_xor(den, 4);
    den += __shfl_xor(den, 8);
    den += __shfl_xor(den, 16);
    den += __shfl_xor(den, 32);
    den = fmaxf(den, 1.0f);

    float acc0 = 0.f, acc1 = 0.f, acc2 = 0.f, acc3 = 0.f;
    #pragma unroll
    for (int i = 0; i < 4; ++i) {
        const int sl = (g << 4) + (i << 2) + q0;
        float wlo = __shfl(wsel, sl);
        float whi = __shfl(wsel, sl + 1);
        half2v a = __builtin_bit_cast(half2v, h01[i].x);
        half2v b = __builtin_bit_cast(half2v, h01[i].y);
        acc0 = fmaf((float)a[0], wlo, acc0);
        acc1 = fmaf((float)b[0], whi, acc1);
        acc2 = fmaf((float)a[1], wlo, acc2);
        acc3 = fmaf((float)b[1], whi, acc3);
    }
    acc0 += __shfl_xor(acc0, 16); acc0 += __shfl_xor(acc0, 32);
    acc1 += __shfl_xor(acc1, 16); acc1 += __shfl_xor(acc1, 32);
    acc2 += __shfl_xor(acc2, 16); acc2 += __shfl_xor(acc2, 32);
    acc3 += __shfl_xor(acc3, 16); acc3 += __shfl_xor(acc3, 32);

    if (doStore) {
        float r = 1.0f / den;
        f32x2 o;
        if (g == 0) { o.x = fmaf(acc0, r, pf.x); o.y = fmaf(acc1, r, pf.y); }
        else        { o.x = fmaf(acc2, r, pf.x); o.y = fmaf(acc3, r, pf.y); }
        __builtin_nontemporal_store(o, reinterpret_cast<f32x2*>(out + n * 64 + g * 32 + k * 2));
    }
}

__global__ __launch_bounds__(256) void pool_kernel(
    const float*  __restrict__ p_coords,   // [N][4]
    const float*  __restrict__ p_features, // [N][64]
    const int*    __restrict__ p_map,      // [N][16]
    const float*  __restrict__ p_mask,     // [N][16]
    const char*   __restrict__ Hvp,        // [M*128 bytes]
    const float4* __restrict__ Vxyz,       // [M]
    float* __restrict__ out,               // [N][64]
    int N)
{
    const int lane = threadIdx.x & 63;
    const int wv   = threadIdx.x >> 6;
    int n0 = __builtin_amdgcn_readfirstlane(((int)blockIdx.x * 4 + wv) * 2);
    if (n0 >= N) return;
    int n1 = n0 + 1;
    const bool has1 = (n1 < N);
    if (!has1) n1 = n0;

    const int g  = lane >> 4;
    const int k  = lane & 15;
    const int q0 = (lane & 1) * 2;
    const int sp = lane >> 2;
    const int j  = lane & 3;

    // ---------------- load phase: both points ----------------
    const int4   m4a  = ((const int4*)  (p_map  + n0 * 16))[g];
    const int4   m4b  = ((const int4*)  (p_map  + n1 * 16))[g];
    const float4 mk4a = ((const float4*)(p_mask + n0 * 16))[g];
    const float4 mk4b = ((const float4*)(p_mask + n1 * 16))[g];
    const unsigned co = (unsigned)k * 8u;

    uint2 ha[4], hb[4];
    #pragma unroll
    for (int i = 0; i < 4; ++i) { ha[i] = make_uint2(0u,0u); hb[i] = make_uint2(0u,0u); }
    if (mk4a.x != 0.f) ha[0] = *(const uint2*)(Hvp + ((unsigned)m4a.x * 128u + co));
    if (mk4a.y != 0.f) ha[1] = *(const uint2*)(Hvp + ((unsigned)m4a.y * 128u + co));
    if (mk4a.z != 0.f) ha[2] = *(const uint2*)(Hvp + ((unsigned)m4a.z * 128u + co));
    if (mk4a.w != 0.f) ha[3] = *(const uint2*)(Hvp + ((unsigned)m4a.w * 128u + co));
    if (mk4b.x != 0.f) hb[0] = *(const uint2*)(Hvp + ((unsigned)m4b.x * 128u + co));
    if (mk4b.y != 0.f) hb[1] = *(const uint2*)(Hvp + ((unsigned)m4b.y * 128u + co));
    if (mk4b.z != 0.f) hb[2] = *(const uint2*)(Hvp + ((unsigned)m4b.z * 128u + co));
    if (mk4b.w != 0.f) hb[3] = *(const uint2*)(Hvp + ((unsigned)m4b.w * 128u + co));

    const int   mia = p_map [n0 * 16 + sp];
    const int   mib = p_map [n1 * 16 + sp];
    const float mka = p_mask[n0 * 16 + sp];
    const float mkb = p_mask[n1 * 16 + sp];
    const float4 va = Vxyz[mia];
    const float4 vb = Vxyz[mib];

    f32x2 pfa = {0.f, 0.f}, pfb = {0.f, 0.f};
    if (g < 2) {
        pfa = __builtin_nontemporal_load(
                reinterpret_cast<const f32x2*>(p_features + n0 * 64 + g * 32 + k * 2));
        pfb = __builtin_nontemporal_load(
                reinterpret_cast<const f32x2*>(p_features + n1 * 64 + g * 32 + k * 2));
    }

    // ---------------- point A ----------------
    {
        const float cx = p_coords[n0 * 4 + 1];
        const float cy = p_coords[n0 * 4 + 2];
        const float cz = p_coords[n0 * 4 + 3];
        float rx = va.x - cx, ry = va.y - cy, rz = va.z - cz;
        float d  = fmaf(rx, rx, fmaf(ry, ry, rz * rz));
        float lo = (j & 1) ? ry * 10.0f : rx * 10.0f;
        float hi = (j & 1) ? d * (1.0f / 0.06f) : rz * 5.0f;
        float wsel = ((j & 2) ? hi : lo) * mka;
        pool_point_compute(n0, g, k, q0, wsel, mka, ha, pfa, out, g < 2);
    }
    // ---------------- point B ----------------
    {
        const float cx = p_coords[n1 * 4 + 1];
        const float cy = p_coords[n1 * 4 + 2];
        const float cz = p_coords[n1 * 4 + 3];
        float rx = vb.x - cx, ry = vb.y - cy, rz = vb.z - cz;
        float d  = fmaf(rx, rx, fmaf(ry, ry, rz * rz));
        float lo = (j & 1) ? ry * 10.0f : rx * 10.0f;
        float hi = (j & 1) ? d * (1.0f / 0.06f) : rz * 5.0f;
        float wsel = ((j & 2) ? hi : lo) * mkb;
        pool_point_compute(n1, g, k, q0, wsel, mkb, hb, pfb, out, (g < 2) && has1);
    }
}

extern "C" void kernel_launch(void* const* d_in, const int* in_sizes, int n_in,
                              void* d_out, int out_size, void* d_ws, size_t ws_size,
                              hipStream_t stream) {
    const int*   v_indices  = (const int*)  d_in[0];
    const float* v_features = (const float*)d_in[1];
    const float* p_coords   = (const float*)d_in[2];
    const float* p_features = (const float*)d_in[3];
    const int*   p_map      = (const int*)  d_in[4];
    const float* p_mask     = (const float*)d_in[5];
    const float* W          = (const float*)d_in[6];
    const float* gamma      = (const float*)d_in[7];
    const float* beta       = (const float*)d_in[8];
    const float* bn_mean    = (const float*)d_in[9];
    const float* bn_var     = (const float*)d_in[10];

    const int M = in_sizes[1] / CH;
    const int N = in_sizes[3] / CH;

    unsigned* Hvp  = (unsigned*)d_ws;                                   // M*128 B
    float4*   Vxyz = (float4*)((char*)d_ws + (size_t)M * 128);          // M*16 B
    half8*    Whp8 = (half8*)((char*)d_ws + (size_t)M * 144);           // 8 KB

    prepack_w<<<1, 512, 0, stream>>>((const float4*)W, Whp8);
    {
        dim3 grid((M + 63) / 64);
        voxel_mlp_mfma<<<grid, 256, 0, stream>>>(
            (const int4*)v_indices, (const float4*)v_features, Whp8,
            gamma, beta, bn_mean, bn_var, Hvp, Vxyz, M);
    }
    {
        dim3 grid((N + 7) / 8);   // 4 waves/block, 2 points/wave
        pool_kernel<<<grid, 256, 0, stream>>>(
            p_coords, p_features, p_map, p_mask,
            (const char*)Hvp, (const float4*)Vxyz, (float*)d_out, N);
    }
}

// Round 10
// 68.404 us; speedup vs baseline: 1.0156x; 1.0156x over previous
//
#include <hip/hip_runtime.h>

#define CH 64

typedef _Float16 half8  __attribute__((ext_vector_type(8)));
typedef _Float16 half2v __attribute__((ext_vector_type(2)));
typedef __fp16   fp16x2 __attribute__((ext_vector_type(2)));
typedef float    f32x4  __attribute__((ext_vector_type(4)));
typedef float    f32x2  __attribute__((ext_vector_type(2)));

// pack 2 f32 -> half2 (RTZ, single VALU op)
__device__ __forceinline__ half2v pk(float a, float b) {
    fp16x2 r = __builtin_amdgcn_cvt_pkrtz(a, b);
    return __builtin_bit_cast(half2v, r);
}

// ---------------------------------------------------------------------------
// Kernel 0: prepack W (f32 [64][64]) into fp16 MFMA B-fragments.
// ---------------------------------------------------------------------------
__global__ __launch_bounds__(512) void prepack_w(
    const float4* __restrict__ Wf4,   // [64*16]
    half8* __restrict__ Whp8)         // [512]
{
    const int t = threadIdx.x;        // 0..511
    const int o    = t & 63;
    const int grp  = t >> 6;          // 0..7
    const int kgrp = grp & 3;
    const int ck   = grp >> 2;
    const int c4   = ck * 8 + kgrp * 2;       // float4 index
    float4 a = Wf4[o * 16 + c4];
    float4 b = Wf4[o * 16 + c4 + 1];
    half8 h;
    half2v p0 = pk(a.x, a.y), p1 = pk(a.z, a.w);
    half2v p2 = pk(b.x, b.y), p3 = pk(b.z, b.w);
    h[0]=p0[0]; h[1]=p0[1]; h[2]=p1[0]; h[3]=p1[1];
    h[4]=p2[0]; h[5]=p2[1]; h[6]=p3[0]; h[7]=p3[1];
    Whp8[t] = h;
}

// ---------------------------------------------------------------------------
// Kernel 1: voxel MLP via MFMA fp16 (f32 accumulate), prepacked W.
// Output row m: 32 dwords, dword j = (h[j], h[j+32]) fp16 pair.
// ---------------------------------------------------------------------------
__global__ __launch_bounds__(256) void voxel_mlp_mfma(
    const int4*   __restrict__ vi4,
    const float4* __restrict__ vf4,
    const half8*  __restrict__ Whp8,
    const float*  __restrict__ gamma,
    const float*  __restrict__ beta,
    const float*  __restrict__ bn_mean,
    const float*  __restrict__ bn_var,
    unsigned*     __restrict__ Hvp,
    float4*       __restrict__ Vxyz,
    int M)
{
    const int t     = threadIdx.x;
    const int lane  = t & 63;
    const int wv    = t >> 6;
    const int row16 = lane & 15;
    const int kgrp  = lane >> 4;
    const int blockRow = blockIdx.x * 64;

    if (t < 64) {
        int r = blockRow + t;
        if (r < M) {
            int4 vi = vi4[r];
            float4 vx;
            vx.x = ((float)vi.w + 0.5f) * 0.1f;
            vx.y = ((float)vi.z + 0.5f) * 0.1f - 40.0f;
            vx.z = ((float)vi.y + 0.5f) * 0.2f - 3.0f;
            vx.w = 0.0f;
            Vxyz[r] = vx;
        }
    }

    // B fragments: straight 16B loads, no conversion
    half8 bfrag[4][2];
    #pragma unroll
    for (int ck = 0; ck < 2; ++ck) {
        #pragma unroll
        for (int ot = 0; ot < 4; ++ot)
            bfrag[ot][ck] = Whp8[(ck * 4 + kgrp) * 64 + ot * 16 + row16];
    }

    // A fragments: v_features rows (f32 -> fp16 via pkrtz)
    const int rbase = blockRow + wv * 16;
    int rc = rbase + row16; if (rc > M - 1) rc = M - 1;
    half8 afrag[2];
    #pragma unroll
    for (int ck = 0; ck < 2; ++ck) {
        int c4 = ck * 8 + kgrp * 2;
        float4 a = vf4[rc * 16 + c4];
        float4 b = vf4[rc * 16 + c4 + 1];
        half8 h;
        half2v p0 = pk(a.x, a.y), p1 = pk(a.z, a.w);
        half2v p2 = pk(b.x, b.y), p3 = pk(b.z, b.w);
        h[0]=p0[0]; h[1]=p0[1]; h[2]=p1[0]; h[3]=p1[1];
        h[4]=p2[0]; h[5]=p2[1]; h[6]=p3[0]; h[7]=p3[1];
        afrag[ck] = h;
    }

    f32x4 acc[4] = {{0.f,0.f,0.f,0.f},{0.f,0.f,0.f,0.f},{0.f,0.f,0.f,0.f},{0.f,0.f,0.f,0.f}};
    #pragma unroll
    for (int ot = 0; ot < 4; ++ot) {
        acc[ot] = __builtin_amdgcn_mfma_f32_16x16x32_f16(afrag[0], bfrag[ot][0], acc[ot], 0, 0, 0);
        acc[ot] = __builtin_amdgcn_mfma_f32_16x16x32_f16(afrag[1], bfrag[ot][1], acc[ot], 0, 0, 0);
    }

    float sc[4], sh[4];
    #pragma unroll
    for (int ot = 0; ot < 4; ++ot) {
        int o = ot * 16 + row16;
        float s = gamma[o] * rsqrtf(bn_var[o] + 1e-5f);
        sc[ot] = s;
        sh[ot] = beta[o] - bn_mean[o] * s;
    }

    #pragma unroll
    for (int reg = 0; reg < 4; ++reg) {
        int row = rbase + kgrp * 4 + reg;
        if (row < M) {
            #pragma unroll
            for (int ot = 0; ot < 2; ++ot) {
                float v0 = fmaxf(fmaf(acc[ot][reg],     sc[ot],     sh[ot]),     0.f);
                float v1 = fmaxf(fmaf(acc[ot + 2][reg], sc[ot + 2], sh[ot + 2]), 0.f);
                half2v p = pk(v0, v1);
                *reinterpret_cast<half2v*>(&Hvp[row * 32 + ot * 16 + row16]) = p;
            }
        }
    }
}

// ---------------------------------------------------------------------------
// Kernel 2: pooling. 2 points per wave, mask-predicated gathers, nt loads
// for single-touch streams (keep L2 for the Hv table), normal stores.
// Prepass lane layout: s = 4g + (lane&3), q = (lane>>2)&3 -> reuses the
// already-loaded m4/mk4 components (no extra scalar VMEM), shfl stays
// within the 16-lane group. den via ballot+popcount (mask is exactly 0/1).
// ---------------------------------------------------------------------------
__device__ __forceinline__ void pool_point_compute(
    int n, int g, int k, int q0,
    float wsel, float den, const uint2* h01,
    f32x2 pf, float* __restrict__ out, bool doStore)
{
    float acc0 = 0.f, acc1 = 0.f, acc2 = 0.f, acc3 = 0.f;
    #pragma unroll
    for (int i = 0; i < 4; ++i) {
        const int sl = (g << 4) + (q0 << 2) + i;   // lane holding w[s=4g+i][q0]
        float wlo = __shfl(wsel, sl);
        float whi = __shfl(wsel, sl + 4);          // q0+1
        half2v a = __builtin_bit_cast(half2v, h01[i].x);
        half2v b = __builtin_bit_cast(half2v, h01[i].y);
        acc0 = fmaf((float)a[0], wlo, acc0);
        acc1 = fmaf((float)b[0], whi, acc1);
        acc2 = fmaf((float)a[1], wlo, acc2);
        acc3 = fmaf((float)b[1], whi, acc3);
    }
    acc0 += __shfl_xor(acc0, 16); acc0 += __shfl_xor(acc0, 32);
    acc1 += __shfl_xor(acc1, 16); acc1 += __shfl_xor(acc1, 32);
    acc2 += __shfl_xor(acc2, 16); acc2 += __shfl_xor(acc2, 32);
    acc3 += __shfl_xor(acc3, 16); acc3 += __shfl_xor(acc3, 32);

    if (doStore) {
        float r = 1.0f / den;
        f32x2 o;
        if (g == 0) { o.x = fmaf(acc0, r, pf.x); o.y = fmaf(acc1, r, pf.y); }
        else        { o.x = fmaf(acc2, r, pf.x); o.y = fmaf(acc3, r, pf.y); }
        *reinterpret_cast<f32x2*>(out + n * 64 + g * 32 + k * 2) = o;
    }
}

__global__ __launch_bounds__(256) void pool_kernel(
    const float*  __restrict__ p_coords,   // [N][4]
    const float*  __restrict__ p_features, // [N][64]
    const int*    __restrict__ p_map,      // [N][16]
    const float*  __restrict__ p_mask,     // [N][16]
    const char*   __restrict__ Hvp,        // [M*128 bytes]
    const float4* __restrict__ Vxyz,       // [M]
    float* __restrict__ out,               // [N][64]
    int N)
{
    const int lane = threadIdx.x & 63;
    const int wv   = threadIdx.x >> 6;
    int n0 = __builtin_amdgcn_readfirstlane(((int)blockIdx.x * 4 + wv) * 2);
    if (n0 >= N) return;
    int n1 = n0 + 1;
    const bool has1 = (n1 < N);
    if (!has1) n1 = n0;

    const int g  = lane >> 4;
    const int k  = lane & 15;
    const int q0 = (lane & 1) * 2;
    const int li = lane & 3;        // prepass: which component of m4/mk4
    const int qq = (lane >> 2) & 3; // prepass: geo component

    // ---------------- load phase: both points ----------------
    const int4   m4a  = ((const int4*)  (p_map  + n0 * 16))[g];
    const int4   m4b  = ((const int4*)  (p_map  + n1 * 16))[g];
    const float4 mk4a = ((const float4*)(p_mask + n0 * 16))[g];
    const float4 mk4b = ((const float4*)(p_mask + n1 * 16))[g];
    const unsigned co = (unsigned)k * 8u;

    uint2 ha[4], hb[4];
    #pragma unroll
    for (int i = 0; i < 4; ++i) { ha[i] = make_uint2(0u,0u); hb[i] = make_uint2(0u,0u); }
    if (mk4a.x != 0.f) ha[0] = *(const uint2*)(Hvp + ((unsigned)m4a.x * 128u + co));
    if (mk4a.y != 0.f) ha[1] = *(const uint2*)(Hvp + ((unsigned)m4a.y * 128u + co));
    if (mk4a.z != 0.f) ha[2] = *(const uint2*)(Hvp + ((unsigned)m4a.z * 128u + co));
    if (mk4a.w != 0.f) ha[3] = *(const uint2*)(Hvp + ((unsigned)m4a.w * 128u + co));
    if (mk4b.x != 0.f) hb[0] = *(const uint2*)(Hvp + ((unsigned)m4b.x * 128u + co));
    if (mk4b.y != 0.f) hb[1] = *(const uint2*)(Hvp + ((unsigned)m4b.y * 128u + co));
    if (mk4b.z != 0.f) hb[2] = *(const uint2*)(Hvp + ((unsigned)m4b.z * 128u + co));
    if (mk4b.w != 0.f) hb[3] = *(const uint2*)(Hvp + ((unsigned)m4b.w * 128u + co));

    // prepass inputs from already-loaded vectors (3 cndmask each, no VMEM)
    const int   mia = (li == 0) ? m4a.x : (li == 1) ? m4a.y : (li == 2) ? m4a.z : m4a.w;
    const int   mib = (li == 0) ? m4b.x : (li == 1) ? m4b.y : (li == 2) ? m4b.z : m4b.w;
    const float mka = (li == 0) ? mk4a.x : (li == 1) ? mk4a.y : (li == 2) ? mk4a.z : mk4a.w;
    const float mkb = (li == 0) ? mk4b.x : (li == 1) ? mk4b.y : (li == 2) ? mk4b.z : mk4b.w;
    const float4 va = Vxyz[mia];
    const float4 vb = Vxyz[mib];

    // den: mask is exactly 0/1; each sample appears 4x (q copies) -> popc>>2
    unsigned long long ba = __ballot(mka != 0.f);
    unsigned long long bb = __ballot(mkb != 0.f);
    const float dena = fmaxf((float)(__popcll(ba) >> 2), 1.0f);
    const float denb = fmaxf((float)(__popcll(bb) >> 2), 1.0f);

    f32x2 pfa = {0.f, 0.f}, pfb = {0.f, 0.f};
    if (g < 2) {
        pfa = __builtin_nontemporal_load(
                reinterpret_cast<const f32x2*>(p_features + n0 * 64 + g * 32 + k * 2));
        pfb = __builtin_nontemporal_load(
                reinterpret_cast<const f32x2*>(p_features + n1 * 64 + g * 32 + k * 2));
    }

    // ---------------- point A ----------------
    {
        const float cx = p_coords[n0 * 4 + 1];
        const float cy = p_coords[n0 * 4 + 2];
        const float cz = p_coords[n0 * 4 + 3];
        float rx = va.x - cx, ry = va.y - cy, rz = va.z - cz;
        float d  = fmaf(rx, rx, fmaf(ry, ry, rz * rz));
        float lo = (qq & 1) ? ry * 10.0f : rx * 10.0f;
        float hi = (qq & 1) ? d * (1.0f / 0.06f) : rz * 5.0f;
        float wsel = (qq & 2) ? hi : lo;   // masked rows have h=0, no mk needed
        pool_point_compute(n0, g, k, q0, wsel, dena, ha, pfa, out, g < 2);
    }
    // ---------------- point B ----------------
    {
        const float cx = p_coords[n1 * 4 + 1];
        const float cy = p_coords[n1 * 4 + 2];
        const float cz = p_coords[n1 * 4 + 3];
        float rx = vb.x - cx, ry = vb.y - cy, rz = vb.z - cz;
        float d  = fmaf(rx, rx, fmaf(ry, ry, rz * rz));
        float lo = (qq & 1) ? ry * 10.0f : rx * 10.0f;
        float hi = (qq & 1) ? d * (1.0f / 0.06f) : rz * 5.0f;
        float wsel = (qq & 2) ? hi : lo;
        pool_point_compute(n1, g, k, q0, wsel, denb, hb, pfb, out, (g < 2) && has1);
    }
}

extern "C" void kernel_launch(void* const* d_in, const int* in_sizes, int n_in,
                              void* d_out, int out_size, void* d_ws, size_t ws_size,
                              hipStream_t stream) {
    const int*   v_indices  = (const int*)  d_in[0];
    const float* v_features = (const float*)d_in[1];
    const float* p_coords   = (const float*)d_in[2];
    const float* p_features = (const float*)d_in[3];
    const int*   p_map      = (const int*)  d_in[4];
    const float* p_mask     = (const float*)d_in[5];
    const float* W          = (const float*)d_in[6];
    const float* gamma      = (const float*)d_in[7];
    const float* beta       = (const float*)d_in[8];
    const float* bn_mean    = (const float*)d_in[9];
    const float* bn_var     = (const float*)d_in[10];

    const int M = in_sizes[1] / CH;
    const int N = in_sizes[3] / CH;

    unsigned* Hvp  = (unsigned*)d_ws;                                   // M*128 B
    float4*   Vxyz = (float4*)((char*)d_ws + (size_t)M * 128);          // M*16 B
    half8*    Whp8 = (half8*)((char*)d_ws + (size_t)M * 144);           // 8 KB

    prepack_w<<<1, 512, 0, stream>>>((const float4*)W, Whp8);
    {
        dim3 grid((M + 63) / 64);
        voxel_mlp_mfma<<<grid, 256, 0, stream>>>(
            (const int4*)v_indices, (const float4*)v_features, Whp8,
            gamma, beta, bn_mean, bn_var, Hvp, Vxyz, M);
    }
    {
        dim3 grid((N + 7) / 8);   // 4 waves/block, 2 points/wave
        pool_kernel<<<grid, 256, 0, stream>>>(
            p_coords, p_features, p_map, p_mask,
            (const char*)Hvp, (const float4*)Vxyz, (float*)d_out, N);
    }
}